// Round 6
// baseline (359.612 us; speedup 1.0000x reference)
//
#include <hip/hip_runtime.h>
#include <hip/hip_bf16.h>

// HyPlant sensor simulator: out[b,i,h,w] = sum_j g[i,j] * L[b,h,w,j] * high_res
// g = row-normalized Gaussian, sigma=(0.27+dsig)*2.3548 (~0.636nm) on a
// 0.866nm grid -> banded. 9-tap band (radius 4) with exact full-row-sum
// normalization; truncation error ~1e-10.
//
// R5b: same as R5 (write-burst enlargement), with the nontemporal store
// using a clang ext_vector float2 (HIP's float2 class is rejected by
// __builtin_nontemporal_store).
//
// R5 rationale: R1-R4 all sit ~214-226us vs ~124us HBM floor with NO
// saturated on-chip pipe. Diagnosis: 256B writes at 1MB stride chip-wide ->
// ~57% DRAM efficiency. Now: block = one 16-channel strip x 512 pixels;
// stages its 24-channel slice column-major in LDS; each lane computes 2
// adjacent pixels -> 512B/instr NT stores, 2KB contiguous per channel.
//
// Shapes fixed by setup_inputs(): B=4, H=512, W=512, S=128.

#define S_CH   128
#define HW_PLN (512 * 512)
#define NTAP   9
#define RADIUS 4
#define PXB    512         // pixels per block
#define SLICE  24          // staged channels per strip (16 + 2*RADIUS)
#define CST    514         // LDS column stride (512 px + 2 pad)
#define CW     16          // channels per strip

typedef float v2f __attribute__((ext_vector_type(2)));

__global__ void hyplant_taps_kernel(const float* __restrict__ sw,
                                    const float* __restrict__ dsig,
                                    float* __restrict__ w_out) {
    const int i = threadIdx.x;          // 0..127
    const int n = S_CH;
    float wl_min = sw[0], wl_max = sw[0];
    for (int j = 1; j < n; ++j) {
        float v = sw[j];
        wl_min = fminf(wl_min, v);
        wl_max = fmaxf(wl_max, v);
    }
    const float span     = wl_max - wl_min;
    const float high_res = span / (float)n;
    const float sigma    = (0.27f + dsig[0]) * 2.3548f;
    const float inv_s    = 1.0f / sigma;
    const float ewl      = sw[i] + 0.04226162119141463f;

    // exact full-row sum for normalization (reference sums all 128 columns)
    float sum = 0.0f;
    for (int j = 0; j < n; ++j) {
        float lhr = wl_min + (span * (float)j) / 127.0f;
        float d   = (lhr - ewl) * inv_s;
        sum += expf(-0.5f * d * d);
    }
    const float scale = high_res / (sum + 1e-6f);

    for (int t = 0; t < NTAP; ++t) {
        int   j = i - RADIUS + t;
        float w = 0.0f;
        if (j >= 0 && j < n) {
            float lhr = wl_min + (span * (float)j) / 127.0f;
            float d   = (lhr - ewl) * inv_s;
            w = expf(-0.5f * d * d) * scale;
        }
        w_out[i * NTAP + t] = w;
    }
}

__global__ __launch_bounds__(256) void hyplant_sim_kernel(
        const float* __restrict__ L,      // [B,512,512,128]
        const float* __restrict__ w_g,    // [128*9] taps
        float* __restrict__ out) {        // [B,128,512,512]
    __shared__ float sm[SLICE * CST];     // column-major: sm[ch][px]

    const int bid = blockIdx.x;
    const int s   = bid & 7;              // strip 0..7 (dispatch-adjacent per region)
    const int rr  = bid >> 3;
    const int b   = rr >> 9;              // image
    const int hw0 = (rr & 511) << 9;      // region base pixel (*512)
    const int tid = threadIdx.x;
    const int c   = s << 4;               // strip base channel (SGPR-uniform)
    const int cb  = c - RADIUS;           // first staged channel (may be -4)

    // stage 512 px x 24 ch slice: 3072 float4 chunks, 12 per thread.
    // chunk source channel jsrc = cb + ch; fully-OOB chunks (strip 0 ch=0,
    // strip 7 ch=20) become zeros -> no partial edge cases.
    const float* base = L + ((size_t)b * HW_PLN + hw0) * S_CH;
#pragma unroll
    for (int k = 0; k < 12; ++k) {
        int idx  = tid + (k << 8);
        int px   = idx / 6;                // 0..511 (magic-mul)
        int ch   = (idx - px * 6) << 2;    // 0,4,8,12,16,20
        int jsrc = cb + ch;
        float4 v = make_float4(0.f, 0.f, 0.f, 0.f);
        if (jsrc >= 0 && jsrc <= S_CH - 4)
            v = *(const float4*)(base + (size_t)px * S_CH + jsrc);
        sm[(ch    ) * CST + px] = v.x;
        sm[(ch + 1) * CST + px] = v.y;
        sm[(ch + 2) * CST + px] = v.z;
        sm[(ch + 3) * CST + px] = v.w;
    }
    __syncthreads();

    // each lane: 2 adjacent pixels, full 16-channel strip.
    const int w  = tid >> 6;              // wave 0..3
    const int l  = tid & 63;
    const int p0 = (w << 7) + (l << 1);   // pixel pair base in region

    float r0[SLICE], r1[SLICE];           // windows, channels [c-4, c+20)
#pragma unroll
    for (int k = 0; k < SLICE; ++k) {     // banks: (2k + 2l) % 32 -> 2-way, free
        r0[k] = sm[k * CST + p0];
        r1[k] = sm[k * CST + p0 + 1];
    }

    // taps: uniform base -> scalar s_load through K$
    const float* __restrict__ wg = w_g + c * NTAP;

    float* outp = out + ((size_t)(b * S_CH + c)) * HW_PLN + hw0 + p0;
#pragma unroll
    for (int il = 0; il < CW; ++il) {
        float a0 = 0.0f, a1 = 0.0f;
#pragma unroll
        for (int t = 0; t < NTAP; ++t) {
            float wt = wg[il * NTAP + t];
            a0 = fmaf(wt, r0[il + t], a0);
            a1 = fmaf(wt, r1[il + t], a1);
        }
        v2f o; o.x = a0; o.y = a1;
        // wave instr = 64 lanes x 8B = 512B contiguous; block writes 2KB/channel
        __builtin_nontemporal_store(o, (v2f*)(outp + (size_t)il * HW_PLN));
    }
}

extern "C" void kernel_launch(void* const* d_in, const int* in_sizes, int n_in,
                              void* d_out, int out_size, void* d_ws, size_t ws_size,
                              hipStream_t stream) {
    const float* L    = (const float*)d_in[0];
    // d_in[1] = delta_lambda (unused by the reference output math)
    const float* dsig = (const float*)d_in[2];
    const float* sw   = (const float*)d_in[3];
    float*       out  = (float*)d_out;
    float*       taps = (float*)d_ws;     // 128*9*4 = 4608 bytes

    hyplant_taps_kernel<<<1, 128, 0, stream>>>(sw, dsig, taps);

    const int total_pixels = in_sizes[0] / S_CH;        // B*H*W = 1048576
    const int grid         = (total_pixels / PXB) * 8;  // 16384 blocks
    hyplant_sim_kernel<<<grid, 256, 0, stream>>>(L, taps, out);
}

// Round 7
// 214.500 us; speedup vs baseline: 1.6765x; 1.6765x over previous
//
#include <hip/hip_runtime.h>
#include <hip/hip_bf16.h>

// HyPlant sensor simulator: out[b,i,h,w] = sum_j g[i,j] * L[b,h,w,j] * high_res
// g = row-normalized Gaussian, sigma=(0.27+dsig)*2.3548 (~0.636nm) on a
// 0.866nm grid -> banded. 9-tap band (radius 4) with exact full-row-sum
// normalization; truncation error ~1e-10.
//
// R6: write-locality. R5 failed from fetch amplification (sliced 96B row
// reads, 917MB fetch) + col-major LDS conflicts; read path reverts to R4's
// proven full-row staging. New: (a) XCD-aware swizzle tile=(bid&7)*1024+
// (bid>>3) so blocks co-resident on an XCD cover CONSECUTIVE pixel tiles
// (per-XCD per-channel write streams become sequential 256B chunks; default
// round-robin made them 2KB-strided); (b) 128-px tiles + pixel-pair lanes
// -> 512B contiguous per store instr, 512B per (block,channel).
//
// Shapes fixed by setup_inputs(): B=4, H=512, W=512, S=128.

#define S_CH   128
#define HW_PLN (512 * 512)
#define TPX    128         // pixels per block
#define RS     137         // LDS row stride: stride-137 lane access -> 2-way banks (free)
#define NTAP   9
#define RADIUS 4
#define CW     16          // channels per wave strip

typedef float v2f __attribute__((ext_vector_type(2)));

__global__ void hyplant_taps_kernel(const float* __restrict__ sw,
                                    const float* __restrict__ dsig,
                                    float* __restrict__ w_out) {
    const int i = threadIdx.x;          // 0..127
    const int n = S_CH;
    float wl_min = sw[0], wl_max = sw[0];
    for (int j = 1; j < n; ++j) {
        float v = sw[j];
        wl_min = fminf(wl_min, v);
        wl_max = fmaxf(wl_max, v);
    }
    const float span     = wl_max - wl_min;
    const float high_res = span / (float)n;
    const float sigma    = (0.27f + dsig[0]) * 2.3548f;
    const float inv_s    = 1.0f / sigma;
    const float ewl      = sw[i] + 0.04226162119141463f;

    // exact full-row sum for normalization (reference sums all 128 columns)
    float sum = 0.0f;
    for (int j = 0; j < n; ++j) {
        float lhr = wl_min + (span * (float)j) / 127.0f;
        float d   = (lhr - ewl) * inv_s;
        sum += expf(-0.5f * d * d);
    }
    const float scale = high_res / (sum + 1e-6f);

    for (int t = 0; t < NTAP; ++t) {
        int   j = i - RADIUS + t;
        float w = 0.0f;
        if (j >= 0 && j < n) {
            float lhr = wl_min + (span * (float)j) / 127.0f;
            float d   = (lhr - ewl) * inv_s;
            w = expf(-0.5f * d * d) * scale;
        }
        w_out[i * NTAP + t] = w;
    }
}

__global__ __launch_bounds__(512, 4) void hyplant_sim_kernel(
        const float* __restrict__ L,      // [B,512,512,128]
        const float* __restrict__ w_g,    // [128*9] taps
        float* __restrict__ out) {        // [B,128,512,512]
    __shared__ float lds[TPX * RS];       // 128 rows x (4 guard | 128 data | 4 guard | 1 pad)

    // XCD swizzle: 8192 blocks, XCD x (bid%8) gets consecutive tiles x*1024..
    const int bid = blockIdx.x;
    const int t0  = ((bid & 7) << 10) + (bid >> 3);   // bijective tile id
    const int b   = t0 >> 11;                          // 2048 tiles per image
    const int hw0 = (t0 & 2047) << 7;                  // tile base pixel (*128)
    const int tid = threadIdx.x;

    // zero the 8 guard floats per row (1024 slots / 512 thr = 2 passes)
#pragma unroll
    for (int k = 0; k < 2; ++k) {
        int idx = tid + (k << 9);
        int row = idx >> 3, q = idx & 7;
        lds[row * RS + (q < 4 ? q : 128 + q)] = 0.0f;
    }

    // stage 128 px x 128 ch: 4096 float4, 8 per thread, fully coalesced
    const float4* src = (const float4*)(L + ((size_t)b * HW_PLN + hw0) * S_CH);
#pragma unroll
    for (int k = 0; k < 8; ++k) {
        int    idx = tid + (k << 9);
        int    p   = idx >> 5, f4 = idx & 31;
        float4 v   = src[idx];
        int    ba  = p * RS + RADIUS + f4 * 4;
        lds[ba]     = v.x;
        lds[ba + 1] = v.y;
        lds[ba + 2] = v.z;
        lds[ba + 3] = v.w;
    }
    __syncthreads();

    // wave w: 16-channel strip c; lane l: adjacent pixel pair (2l, 2l+1)
    const int l  = tid & 63;
    const int c  = __builtin_amdgcn_readfirstlane((tid >> 6) << 4); // 0,16,..,112
    const int p0 = l << 1;

    float r0[CW + 2 * RADIUS], r1[CW + 2 * RADIUS];   // windows [c-4, c+20)
    const int rb0 = p0 * RS + c;
#pragma unroll
    for (int k = 0; k < CW + 2 * RADIUS; ++k) {
        r0[k] = lds[rb0 + k];
        r1[k] = lds[rb0 + RS + k];
    }

    // taps: wave-uniform base -> scalar s_load through K$
    const float* __restrict__ wg = w_g + c * NTAP;

    float* outp = out + ((size_t)(b * S_CH + c)) * HW_PLN + hw0 + p0;
#pragma unroll
    for (int il = 0; il < CW; ++il) {
        float a0 = 0.0f, a1 = 0.0f;
#pragma unroll
        for (int t = 0; t < NTAP; ++t) {
            float wt = wg[il * NTAP + t];
            a0 = fmaf(wt, r0[il + t], a0);
            a1 = fmaf(wt, r1[il + t], a1);
        }
        v2f o; o.x = a0; o.y = a1;
        // 64 lanes x 8B contiguous = 512B/instr; block: 512B per channel
        __builtin_nontemporal_store(o, (v2f*)(outp + (size_t)il * HW_PLN));
    }
}

extern "C" void kernel_launch(void* const* d_in, const int* in_sizes, int n_in,
                              void* d_out, int out_size, void* d_ws, size_t ws_size,
                              hipStream_t stream) {
    const float* L    = (const float*)d_in[0];
    // d_in[1] = delta_lambda (unused by the reference output math)
    const float* dsig = (const float*)d_in[2];
    const float* sw   = (const float*)d_in[3];
    float*       out  = (float*)d_out;
    float*       taps = (float*)d_ws;     // 128*9*4 = 4608 bytes

    hyplant_taps_kernel<<<1, 128, 0, stream>>>(sw, dsig, taps);

    const int total_pixels = in_sizes[0] / S_CH;     // B*H*W = 1048576
    const int grid         = total_pixels / TPX;     // 8192 blocks
    hyplant_sim_kernel<<<grid, 512, 0, stream>>>(L, taps, out);
}